// Round 1
// baseline (175.475 us; speedup 1.0000x reference)
//
#include <hip/hip_runtime.h>

// Camera back-projection: out[n,0,ix,iy,iz] = 1 - 128 * tdf
// tdf = min(|zc - d|, 1/128) if in frustum else 1/128
// zc = cam_dist - z ; u = fl*x/zc + 239.5 ; v = fl*y/zc + 239.5
// d = depth[n, clip(round(v)), clip(round(u))]
//
// RES=128, IMG=480, one thread handles 4 consecutive iz -> float4 store.
// Exact IEEE division + rintf (half-to-even) to match numpy bit-for-bit:
// a reciprocal shortcut flips O(1e3) pixel roundings out of 67M coords.

#define RES 128
#define IMG 480

__global__ __launch_bounds__(256) void cbp_kernel(
    const float* __restrict__ depth,
    const float* __restrict__ fl,
    const float* __restrict__ cam_dist,
    float4* __restrict__ out)
{
    int tid = blockIdx.x * blockDim.x + threadIdx.x;
    // tid layout: [n (4b)] [ix (7b)] [iy (7b)] [izq (5b)]
    int izq = tid & 31;          // 32 groups of 4 z
    int iy  = (tid >> 5) & 127;
    int ix  = (tid >> 12) & 127;
    int n   = tid >> 19;

    float flv = fl[n];           // fl is (N,1)
    float cd  = cam_dist[n];

    float x = (ix + 0.5f) / 128.0f - 0.5f;   // exact (pow2 div)
    float y = (iy + 0.5f) / 128.0f - 0.5f;
    float fx = flv * x;                       // matches (fl_ * x)
    float fy = flv * y;

    const float* __restrict__ dimg = depth + (size_t)n * (IMG * IMG);

    const float trunc = 1.0f / 128.0f;
    float r[4];
    int iz0 = izq * 4;

#pragma unroll
    for (int j = 0; j < 4; ++j) {
        int iz = iz0 + j;
        float z  = (iz + 0.5f) / 128.0f - 0.5f;
        float zc = cd - z;
        float u = fx / zc + 239.5f;   // IEEE div, same op order as reference
        float v = fy / zc + 239.5f;
        float ur = rintf(u);          // round half-to-even == np.round
        float vr = rintf(v);
        int ui = (int)fminf(fmaxf(ur, 0.0f), 479.0f);
        int vi = (int)fminf(fmaxf(vr, 0.0f), 479.0f);
        float d = dimg[vi * IMG + ui];
        bool in_f = (u >= 0.0f) && (u <= 479.0f) &&
                    (v >= 0.0f) && (v <= 479.0f) &&
                    (d > 0.0f) && (zc > 0.0f);
        float tdf = fminf(fabsf(zc - d), trunc);
        tdf = in_f ? tdf : trunc;
        r[j] = 1.0f - 128.0f * tdf;   // 128*tdf exact (pow2), fma-safe
    }

    out[tid] = make_float4(r[0], r[1], r[2], r[3]);
}

extern "C" void kernel_launch(void* const* d_in, const int* in_sizes, int n_in,
                              void* d_out, int out_size, void* d_ws, size_t ws_size,
                              hipStream_t stream) {
    const float* depth = (const float*)d_in[0];
    const float* fl    = (const float*)d_in[1];
    const float* cd    = (const float*)d_in[2];
    float4* out        = (float4*)d_out;

    int N = in_sizes[1];                      // fl has N elements (N,1)
    long long total_threads = (long long)N * RES * RES * (RES / 4);
    int block = 256;
    int grid = (int)((total_threads + block - 1) / block);

    cbp_kernel<<<grid, block, 0, stream>>>(depth, fl, cd, out);
}